// Round 3
// baseline (19548.137 us; speedup 1.0000x reference)
//
#include <hip/hip_runtime.h>
#include <hip/hip_bf16.h>
#include <cstdint>

// Seq2Seq LSTM: B=2048, H=512, I=64, T_enc=256, T_dec=10.
// Persistent kernel, 256 WGs x 512 threads (8 waves, 2/SIMD).
// gates = [x|h] @ [Wih|Whh]^T via mfma(W-frag, h-frag): thread holds 4 gates
// of one unit in one f32x4 acc. Whh resident in LDS (128KB); h staged in a
// 2x16KB LDS double-buffer with counted vmcnt; x pre-split hi/lo in fragment
// layout; x-part weights + biases in registers; c state in registers.

#define B_    2048
#define H_    512
#define I_    64
#define TENC  256
#define TDEC  10
#define WIMG2 65536   // u16 per nt Whh image: 8 blk * 128 row * 64 col

typedef __bf16 bf16x8 __attribute__((ext_vector_type(8)));
typedef float  f32x4  __attribute__((ext_vector_type(4)));
typedef unsigned int   u32;
typedef unsigned short u16;

union BCV { uint4 u; bf16x8 b; };

__device__ __forceinline__ u16 f2bf_rne(float f){
  u32 b = __float_as_uint(f);
  b += 0x7FFFu + ((b >> 16) & 1u);
  return (u16)(b >> 16);
}
__device__ __forceinline__ float bf2f(u16 u){ return __uint_as_float(((u32)u) << 16); }

__device__ __forceinline__ void gl_lds16(const void* g, void* l){
  __builtin_amdgcn_global_load_lds((const __attribute__((address_space(1))) u32*)g,
                                   (__attribute__((address_space(3))) u32*)l, 16, 0, 0);
}

__device__ __forceinline__ float sigm(float x){ return 1.f / (1.f + __expf(-x)); }
__device__ __forceinline__ float tanhfast(float x){ return 1.f - 2.f / (1.f + __expf(2.f * x)); }

#define MFMA16 __builtin_amdgcn_mfma_f32_16x16x32_bf16

__device__ __forceinline__ bf16x8 ld_bf8(const u16* p){
  BCV cv; cv.u = *(const uint4*)p; return cv.b;
}

__device__ __forceinline__ void cvt_x8(const float* p, bf16x8& hi, bf16x8& lo){
  float4 a = ((const float4*)p)[0];
  float4 b = ((const float4*)p)[1];
  float f[8] = {a.x, a.y, a.z, a.w, b.x, b.y, b.z, b.w};
  u32 hw[4], lw[4];
  #pragma unroll
  for (int e = 0; e < 4; ++e) {
    float f0 = f[e*2], f1 = f[e*2+1];
    u16 h0 = f2bf_rne(f0), h1 = f2bf_rne(f1);
    u16 l0 = f2bf_rne(f0 - bf2f(h0)), l1 = f2bf_rne(f1 - bf2f(h1));
    hw[e] = (u32)h0 | ((u32)h1 << 16);
    lw[e] = (u32)l0 | ((u32)l1 << 16);
  }
  BCV ch, cl;
  ch.u = make_uint4(hw[0], hw[1], hw[2], hw[3]);
  cl.u = make_uint4(lw[0], lw[1], lw[2], lw[3]);
  hi = ch.b; lo = cl.b;
}

// ---------------------------------------------------------------------------
// Pack kernels. Packed-col permutation: c (0..2047) -> n = (c&3)*512 + (c>>2)
// (4 gates of one unit are consecutive packed cols).
// ---------------------------------------------------------------------------
__global__ __launch_bounds__(256) void pack_whh(const float* __restrict__ Whh,
                                                u16* __restrict__ img)
{
  int idx = blockIdx.x * 256 + threadIdx.x;
  if (idx >= 16 * WIMG2) return;
  int nt = idx >> 16, rem = idx & 65535;
  int blk = rem >> 13, r2 = rem & 8191;
  int row = r2 >> 6, col = r2 & 63;
  int sc = col >> 3, e = col & 7;
  int lc = ((sc ^ (row & 7)) << 3) + e;
  int n = (row & 3) * 512 + nt * 32 + (row >> 2);
  img[idx] = f2bf_rne(Whh[(size_t)n * 512 + blk * 64 + lc]);
}

__global__ __launch_bounds__(256) void pack_xw(const float* __restrict__ Wih,
                                               u16* __restrict__ xwf)
{
  int idx = blockIdx.x * 256 + threadIdx.x;
  if (idx >= 64 * 8 * 512) return;
  int strip = idx >> 12, rem = idx & 4095;
  int frag = rem >> 9, le = rem & 511;
  int lane = le >> 3, e = le & 7;
  int part = frag >> 2, ks = (frag >> 1) & 1, ni = frag & 1;
  int nt = strip >> 2, nh = strip & 3;
  int c = nt * 128 + nh * 32 + ni * 16 + (lane & 15);
  int k = ks * 32 + (lane >> 4) * 8 + e;
  int n = (c & 3) * 512 + (c >> 2);
  float w = Wih[n * 64 + k];
  u16 h = f2bf_rne(w);
  xwf[idx] = part ? f2bf_rne(w - bf2f(h)) : h;
}

__global__ __launch_bounds__(256) void pack_bias(const float* __restrict__ bih,
                                                 const float* __restrict__ bhh,
                                                 float* __restrict__ bias_pk)
{
  int c = blockIdx.x * 256 + threadIdx.x;
  if (c >= 2048) return;
  int n = (c & 3) * 512 + (c >> 2);
  bias_pk[c] = bih[n] + bhh[n];
}

__global__ __launch_bounds__(256) void transpose_wd(const float* __restrict__ Wd,
                                                    float* __restrict__ WdT)
{
  int idx = blockIdx.x * 256 + threadIdx.x;
  if (idx >= I_ * H_) return;
  int n = idx >> 9, k = idx & 511;
  WdT[k * 64 + n] = Wd[idx];
}

// x -> hi/lo bf16 fragment layout: xf[(t*128+rb)*2048 + (part*2+kf)*512 + lane*8]
__global__ __launch_bounds__(64) void prefrag_x(const float* __restrict__ x,
                                                u16* __restrict__ xf)
{
  int wg = blockIdx.x;
  int t = wg >> 7, rb = wg & 127;
  int l = threadIdx.x;
  __shared__ float tile[16][65];
  #pragma unroll
  for (int row = 0; row < 16; ++row)
    tile[row][l] = x[(((size_t)(rb * 16 + row)) * 256 + t) * 64 + l];
  __syncthreads();
  int lr = l & 15, lgp = l >> 4;
  size_t base = ((size_t)t * 128 + rb) * 2048;
  #pragma unroll
  for (int kf = 0; kf < 2; ++kf) {
    u32 hw[4], lw[4];
    #pragma unroll
    for (int e2 = 0; e2 < 4; ++e2) {
      float f0 = tile[lr][kf * 32 + lgp * 8 + e2 * 2];
      float f1 = tile[lr][kf * 32 + lgp * 8 + e2 * 2 + 1];
      u16 h0 = f2bf_rne(f0), h1 = f2bf_rne(f1);
      u16 l0 = f2bf_rne(f0 - bf2f(h0)), l1 = f2bf_rne(f1 - bf2f(h1));
      hw[e2] = (u32)h0 | ((u32)h1 << 16);
      lw[e2] = (u32)l0 | ((u32)l1 << 16);
    }
    *(uint4*)(xf + base + (0 * 2 + kf) * 512 + l * 8) = make_uint4(hw[0], hw[1], hw[2], hw[3]);
    *(uint4*)(xf + base + (1 * 2 + kf) * 512 + l * 8) = make_uint4(lw[0], lw[1], lw[2], lw[3]);
  }
}

// ---------------------------------------------------------------------------
__device__ __forceinline__ void stage_whh(const u16* src, char* smem, int tid){
  #pragma unroll
  for (int it = 0; it < 16; ++it)
    gl_lds16(src + it * 4096 + tid * 8, smem + it * 8192 + tid * 16);
}

__device__ __forceinline__ void stage_h(const u16* hbase, char* dst, int kb, int tid){
  #pragma unroll
  for (int q = 0; q < 2; ++q) {
    int row = q * 64 + (tid >> 3);
    int sc = (tid & 7) ^ (row & 7);
    gl_lds16(hbase + (size_t)row * 512 + kb * 64 + sc * 8, dst + q * 8192 + tid * 16);
  }
}

__device__ __forceinline__ void load_xw(const u16* basep, int lane,
                                        bf16x8 whiR[2][2], bf16x8 wloR[2][2]){
  #pragma unroll
  for (int part = 0; part < 2; ++part)
    #pragma unroll
    for (int ks = 0; ks < 2; ++ks)
      #pragma unroll
      for (int ni = 0; ni < 2; ++ni) {
        bf16x8 v = ld_bf8(basep + ((part * 2 + ks) * 2 + ni) * 512 + lane * 8);
        if (part == 0) whiR[ks][ni] = v; else wloR[ks][ni] = v;
      }
}

__device__ __forceinline__ void gbar(u32* cptr, int& ev){
  __threadfence();
  __syncthreads();
  ++ev;
  if (threadIdx.x == 0) {
    __hip_atomic_fetch_add(cptr, 1u, __ATOMIC_RELEASE, __HIP_MEMORY_SCOPE_AGENT);
    u32 target = (u32)(ev * 16);
    while (__hip_atomic_load(cptr, __ATOMIC_ACQUIRE, __HIP_MEMORY_SCOPE_AGENT) < target)
      __builtin_amdgcn_s_sleep(1);
  }
  __syncthreads();
}

// ---------------------------------------------------------------------------
__global__ __launch_bounds__(512, 2) void lstm_persistent(
    const float* __restrict__ x, const u16* __restrict__ xf, int use_xf,
    const u16* __restrict__ WhhE, const u16* __restrict__ WhhD,
    const u16* __restrict__ xwE, const u16* __restrict__ xwD,
    const float* __restrict__ biasE, const float* __restrict__ biasD,
    u16* __restrict__ hb0, u16* __restrict__ hb1,
    float* __restrict__ hf32, float* __restrict__ dout,
    const float* __restrict__ WdT, const float* __restrict__ ldb,
    const float* __restrict__ loW, const float* __restrict__ lob,
    float* __restrict__ out, u32* __restrict__ cnt)
{
  extern __shared__ char smem[];
  const int HB = 131072;
  const int tid = threadIdx.x;
  const int bid = blockIdx.x;
  const int mt = ((bid & 7) << 1) | ((bid >> 3) & 1);  // group members share XCD
  const int nt = bid >> 4;
  const int wid = tid >> 6, lane = tid & 63;
  const int mh = wid >> 2, nh = wid & 3;
  const int lr = lane & 15, lgp = lane >> 4;
  u32* cptr = cnt + mt * 16;   // 64B-padded per-group counter

  stage_whh(WhhE + (size_t)nt * WIMG2, smem, tid);
  bf16x8 whiR[2][2], wloR[2][2];
  load_xw(xwE + (size_t)(nt * 4 + nh) * 8 * 512, lane, whiR, wloR);
  f32x4 bvec[2];
  bvec[0] = *(const f32x4*)(biasE + nt * 128 + nh * 32 + lgp * 4);
  bvec[1] = *(const f32x4*)(biasE + nt * 128 + nh * 32 + 16 + lgp * 4);
  asm volatile("s_waitcnt vmcnt(0)" ::: "memory");
  __syncthreads();

  float creg[4][2];
  #pragma unroll
  for (int a = 0; a < 4; ++a) { creg[a][0] = 0.f; creg[a][1] = 0.f; }

  int ev = 0;
  for (int t = 0; t < TENC + TDEC; ++t) {
    if (t == TENC) {
      stage_whh(WhhD + (size_t)nt * WIMG2, smem, tid);
      load_xw(xwD + (size_t)(nt * 4 + nh) * 8 * 512, lane, whiR, wloR);
      bvec[0] = *(const f32x4*)(biasD + nt * 128 + nh * 32 + lgp * 4);
      bvec[1] = *(const f32x4*)(biasD + nt * 128 + nh * 32 + 16 + lgp * 4);
      asm volatile("s_waitcnt vmcnt(0)" ::: "memory");
      __syncthreads();
    }
    const u16* __restrict__ h_in  = (t & 1) ? hb1 : hb0;
    u16*       __restrict__ h_out = (t & 1) ? hb0 : hb1;

    // ---- x fragments (issued before the group barrier; independent of h) ----
    bf16x8 xh[4][2], xl[4][2];
    if (use_xf && t <= TENC) {
      int tx = (t < TENC) ? t : 255;
      #pragma unroll
      for (int mi = 0; mi < 4; ++mi) {
        const u16* fb = xf + ((size_t)tx * 128 + mt * 8 + mh * 4 + mi) * 2048;
        xh[mi][0] = ld_bf8(fb +        lane * 8);
        xh[mi][1] = ld_bf8(fb +  512 + lane * 8);
        xl[mi][0] = ld_bf8(fb + 1024 + lane * 8);
        xl[mi][1] = ld_bf8(fb + 1536 + lane * 8);
      }
    } else {
      #pragma unroll
      for (int mi = 0; mi < 4; ++mi) {
        int brow = mt * 128 + mh * 64 + mi * 16 + lr;
        const float* p = (t > TENC) ? (dout + (size_t)brow * 64)
                                    : (x + ((size_t)brow * 256 + ((t < TENC) ? t : 255)) * 64);
        cvt_x8(p + lgp * 8,      xh[mi][0], xl[mi][0]);
        cvt_x8(p + 32 + lgp * 8, xh[mi][1], xl[mi][1]);
      }
    }

    gbar(cptr, ev);   // h(t-1) visible group-wide

    const u16* hbase = h_in + (size_t)mt * 128 * 512;
    stage_h(hbase, smem + HB,         0, tid);
    stage_h(hbase, smem + HB + 16384, 1, tid);

    f32x4 acc[4][2];
    #pragma unroll
    for (int a = 0; a < 4; ++a) {
      acc[a][0] = (f32x4){0.f, 0.f, 0.f, 0.f};
      acc[a][1] = (f32x4){0.f, 0.f, 0.f, 0.f};
    }

    // ---- x-part MFMAs (overlap h-stage latency) ----
    #pragma unroll
    for (int ks = 0; ks < 2; ++ks)
      #pragma unroll
      for (int mi = 0; mi < 4; ++mi)
        #pragma unroll
        for (int ni = 0; ni < 2; ++ni) {
          acc[mi][ni] = MFMA16(whiR[ks][ni], xh[mi][ks], acc[mi][ni], 0, 0, 0);
          acc[mi][ni] = MFMA16(wloR[ks][ni], xh[mi][ks], acc[mi][ni], 0, 0, 0);
          acc[mi][ni] = MFMA16(whiR[ks][ni], xl[mi][ks], acc[mi][ni], 0, 0, 0);
        }

    // ---- h-part: 8 chunks, LDS dbuf, counted vmcnt, raw barriers ----
    #pragma unroll
    for (int kb = 0; kb < 8; ++kb) {
      if (kb < 7) { asm volatile("s_waitcnt vmcnt(2)" ::: "memory"); }
      else        { asm volatile("s_waitcnt vmcnt(0)" ::: "memory"); }
      __builtin_amdgcn_s_barrier();
      const char* hc = smem + HB + (kb & 1) * 16384;
      #pragma unroll
      for (int ks = 0; ks < 2; ++ks) {
        bf16x8 wf[2], hfr[4];
        #pragma unroll
        for (int ni = 0; ni < 2; ++ni) {
          int crow = nh * 32 + ni * 16 + lr;
          wf[ni] = *(const bf16x8*)(smem + kb * 16384 + crow * 128 +
                                    (((ks * 4 + lgp) ^ (crow & 7)) << 4));
        }
        #pragma unroll
        for (int mi = 0; mi < 4; ++mi) {
          int hr = mh * 64 + mi * 16 + lr;
          hfr[mi] = *(const bf16x8*)(hc + hr * 128 +
                                     (((ks * 4 + lgp) ^ (hr & 7)) << 4));
        }
        #pragma unroll
        for (int mi = 0; mi < 4; ++mi)
          #pragma unroll
          for (int ni = 0; ni < 2; ++ni)
            acc[mi][ni] = MFMA16(wf[ni], hfr[mi], acc[mi][ni], 0, 0, 0);
      }
      asm volatile("s_waitcnt lgkmcnt(0)" ::: "memory");
      __builtin_amdgcn_s_barrier();
      if (kb < 6) stage_h(hbase, smem + HB + (kb & 1) * 16384, kb + 2, tid);
    }

    // ---- fused LSTM epilogue: acc[mi][ni] = (i,f,g,o) of unit j ----
    #pragma unroll
    for (int mi = 0; mi < 4; ++mi)
      #pragma unroll
      for (int ni = 0; ni < 2; ++ni) {
        f32x4 g = acc[mi][ni];
        float gi = g[0] + bvec[ni][0];
        float gf = g[1] + bvec[ni][1];
        float gg = g[2] + bvec[ni][2];
        float go = g[3] + bvec[ni][3];
        float c0 = creg[mi][ni];
        float cn = sigm(gf) * c0 + sigm(gi) * tanhfast(gg);
        float hn = sigm(go) * tanhfast(cn);
        creg[mi][ni] = cn;
        int brow = mt * 128 + mh * 64 + mi * 16 + lr;
        int j = nt * 32 + nh * 8 + ni * 4 + lgp;
        h_out[(size_t)brow * 512 + j] = f2bf_rne(hn);
        if (t >= TENC) hf32[(size_t)brow * 512 + j] = hn;
      }

    // ---- decoder projections ----
    if (t >= TENC) {
      gbar(cptr, ev);   // hf32 visible
      int d = t - TENC;
      int b = mt * 128 + nt * 8 + wid;
      const float* hr = hf32 + (size_t)b * 512;
      float a2 = ldb[lane];
      #pragma unroll 4
      for (int k = 0; k < 512; k += 4) {
        float4 hv = *(const float4*)(hr + k);
        a2 += hv.x * WdT[k * 64 + lane] + hv.y * WdT[(k + 1) * 64 + lane]
            + hv.z * WdT[(k + 2) * 64 + lane] + hv.w * WdT[(k + 3) * 64 + lane];
      }
      dout[(size_t)b * 64 + lane] = a2;
      float yv = a2 * loW[lane];
      #pragma unroll
      for (int off = 32; off; off >>= 1) yv += __shfl_xor(yv, off, 64);
      if (lane == 0) out[(size_t)b * TDEC + d] = yv + lob[0];
      if (t < TENC + TDEC - 1) gbar(cptr, ev);   // dout visible for next x
    }
  }
}

// ---------------------------------------------------------------------------
extern "C" void kernel_launch(void* const* d_in, const int* in_sizes, int n_in,
                              void* d_out, int out_size, void* d_ws, size_t ws_size,
                              hipStream_t stream)
{
  const float* x    = (const float*)d_in[0];
  const float* eWih = (const float*)d_in[1];
  const float* eWhh = (const float*)d_in[2];
  const float* ebih = (const float*)d_in[3];
  const float* ebhh = (const float*)d_in[4];
  const float* dWih = (const float*)d_in[5];
  const float* dWhh = (const float*)d_in[6];
  const float* dbih = (const float*)d_in[7];
  const float* dbhh = (const float*)d_in[8];
  const float* ldW  = (const float*)d_in[9];
  const float* ldbp = (const float*)d_in[10];
  const float* loW  = (const float*)d_in[11];
  const float* lob  = (const float*)d_in[12];
  float* out = (float*)d_out;

  char* ws = (char*)d_ws;
  size_t o = 0;
  auto alloc = [&](size_t bytes){ size_t r = o; o += (bytes + 255) & ~(size_t)255; return r; };
  u16*   WhhIE = (u16*)  (ws + alloc((size_t)16 * WIMG2 * 2));
  u16*   WhhID = (u16*)  (ws + alloc((size_t)16 * WIMG2 * 2));
  u16*   xwE   = (u16*)  (ws + alloc((size_t)64 * 8 * 512 * 2));
  u16*   xwD   = (u16*)  (ws + alloc((size_t)64 * 8 * 512 * 2));
  float* biasE = (float*)(ws + alloc(2048 * 4));
  float* biasD = (float*)(ws + alloc(2048 * 4));
  float* WdT   = (float*)(ws + alloc((size_t)I_ * H_ * 4));
  u16*   hb0   = (u16*)  (ws + alloc((size_t)B_ * H_ * 2));
  u16*   hb1   = (u16*)  (ws + alloc((size_t)B_ * H_ * 2));
  float* hf32  = (float*)(ws + alloc((size_t)B_ * H_ * 4));
  float* dout  = (float*)(ws + alloc((size_t)B_ * I_ * 4));
  u32*   cnt   = (u32*)  (ws + alloc(16 * 64));
  size_t xf_off = alloc((size_t)256 * 128 * 2048 * 2);   // 128 MiB
  int use_xf = (o <= ws_size) ? 1 : 0;
  u16* xf = use_xf ? (u16*)(ws + xf_off) : (u16*)(ws);   // dummy if unused
  (void)in_sizes; (void)n_in; (void)out_size;

  pack_whh<<<(16 * WIMG2 + 255) / 256, 256, 0, stream>>>(eWhh, WhhIE);
  pack_whh<<<(16 * WIMG2 + 255) / 256, 256, 0, stream>>>(dWhh, WhhID);
  pack_xw<<<(64 * 8 * 512 + 255) / 256, 256, 0, stream>>>(eWih, xwE);
  pack_xw<<<(64 * 8 * 512 + 255) / 256, 256, 0, stream>>>(dWih, xwD);
  pack_bias<<<8, 256, 0, stream>>>(ebih, ebhh, biasE);
  pack_bias<<<8, 256, 0, stream>>>(dbih, dbhh, biasD);
  transpose_wd<<<(I_ * H_ + 255) / 256, 256, 0, stream>>>(ldW, WdT);
  if (use_xf)
    prefrag_x<<<256 * 128, 64, 0, stream>>>(x, xf);
  hipMemsetAsync(hb0, 0, (size_t)B_ * H_ * 2, stream);
  hipMemsetAsync(cnt, 0, 16 * 64, stream);

  static bool attr_set = false;
  if (!attr_set) {
    hipFuncSetAttribute((const void*)lstm_persistent,
                        hipFuncAttributeMaxDynamicSharedMemorySize, 163840);
    attr_set = true;
  }

  const float* xp = x; const u16* xfp = xf; int uxf = use_xf;
  const u16 *we = WhhIE, *wd = WhhID, *xe = xwE, *xd = xwD;
  const float *be = biasE, *bd = biasD, *wdt = WdT, *lb = ldbp, *lw = loW, *lo2 = lob;
  u16 *h0 = hb0, *h1 = hb1;
  float *hf = hf32, *dp = dout, *op = out;
  u32* cp = cnt;
  void* kargs[] = { (void*)&xp, (void*)&xfp, (void*)&uxf, (void*)&we, (void*)&wd,
                    (void*)&xe, (void*)&xd, (void*)&be, (void*)&bd,
                    (void*)&h0, (void*)&h1, (void*)&hf, (void*)&dp, (void*)&wdt,
                    (void*)&lb, (void*)&lw, (void*)&lo2, (void*)&op, (void*)&cp };
  hipError_t e = hipLaunchCooperativeKernel((const void*)lstm_persistent,
                                            dim3(256), dim3(512), kargs, 163840, stream);
  if (e != hipSuccess) {
    lstm_persistent<<<256, 512, 163840, stream>>>(xp, xfp, uxf, we, wd, xe, xd,
                                                  be, bd, h0, h1, hf, dp, wdt,
                                                  lb, lw, lo2, op, cp);
  }
}

// Round 4
// 12736.474 us; speedup vs baseline: 1.5348x; 1.5348x over previous
//
#include <hip/hip_runtime.h>
#include <hip/hip_bf16.h>
#include <cstdint>

// Seq2Seq LSTM: B=2048, H=512, I=64, T_enc=256, T_dec=10.
// Persistent kernel, 256 WGs x 512 threads (8 waves), 16 groups x 16 WGs,
// one device-scope group barrier per step. Whh resident in LDS (128KB).
// h exchanged between steps in MFMA-fragment layout (coalesced 16B/lane
// reads, no LDS staging, no in-loop barriers). x pre-fragmented hi/lo bf16.
// c state in registers. x-part MFMAs before the barrier (kills live range).

#define B_    2048
#define H_    512
#define I_    64
#define TENC  256
#define TDEC  10
#define WIMG2 65536   // u16 per nt Whh image: 8 blk * 128 row * 64 col

typedef __bf16 bf16x8 __attribute__((ext_vector_type(8)));
typedef float  f32x4  __attribute__((ext_vector_type(4)));
typedef unsigned int   u32;
typedef unsigned short u16;

union BCV { uint4 u; bf16x8 b; };

__device__ __forceinline__ u16 f2bf_rne(float f){
  u32 b = __float_as_uint(f);
  b += 0x7FFFu + ((b >> 16) & 1u);
  return (u16)(b >> 16);
}
__device__ __forceinline__ float bf2f(u16 u){ return __uint_as_float(((u32)u) << 16); }

__device__ __forceinline__ void gl_lds16(const void* g, void* l){
  __builtin_amdgcn_global_load_lds((const __attribute__((address_space(1))) u32*)g,
                                   (__attribute__((address_space(3))) u32*)l, 16, 0, 0);
}

__device__ __forceinline__ float sigm(float x){ return 1.f / (1.f + __expf(-x)); }
__device__ __forceinline__ float tanhfast(float x){ return 1.f - 2.f / (1.f + __expf(2.f * x)); }

#define MFMA16 __builtin_amdgcn_mfma_f32_16x16x32_bf16

__device__ __forceinline__ bf16x8 ld_bf8(const u16* p){
  BCV cv; cv.u = *(const uint4*)p; return cv.b;
}

__device__ __forceinline__ void cvt_x8(const float* p, bf16x8& hi, bf16x8& lo){
  float4 a = ((const float4*)p)[0];
  float4 b = ((const float4*)p)[1];
  float f[8] = {a.x, a.y, a.z, a.w, b.x, b.y, b.z, b.w};
  u32 hw[4], lw[4];
  #pragma unroll
  for (int e = 0; e < 4; ++e) {
    float f0 = f[e*2], f1 = f[e*2+1];
    u16 h0 = f2bf_rne(f0), h1 = f2bf_rne(f1);
    u16 l0 = f2bf_rne(f0 - bf2f(h0)), l1 = f2bf_rne(f1 - bf2f(h1));
    hw[e] = (u32)h0 | ((u32)h1 << 16);
    lw[e] = (u32)l0 | ((u32)l1 << 16);
  }
  BCV ch, cl;
  ch.u = make_uint4(hw[0], hw[1], hw[2], hw[3]);
  cl.u = make_uint4(lw[0], lw[1], lw[2], lw[3]);
  hi = ch.b; lo = cl.b;
}

// ---------------------------------------------------------------------------
// Packing. Packed-col permutation: c (0..2047) -> n = (c&3)*512 + (c>>2).
// ---------------------------------------------------------------------------
__global__ __launch_bounds__(256) void pack_whh(const float* __restrict__ Whh,
                                                u16* __restrict__ img)
{
  int idx = blockIdx.x * 256 + threadIdx.x;
  if (idx >= 16 * WIMG2) return;
  int nt = idx >> 16, rem = idx & 65535;
  int blk = rem >> 13, r2 = rem & 8191;
  int row = r2 >> 6, col = r2 & 63;
  int sc = col >> 3, e = col & 7;
  int lc = ((sc ^ (row & 7)) << 3) + e;
  int n = (row & 3) * 512 + nt * 32 + (row >> 2);
  img[idx] = f2bf_rne(Whh[(size_t)n * 512 + blk * 64 + lc]);
}

__global__ __launch_bounds__(256) void pack_xw(const float* __restrict__ Wih,
                                               u16* __restrict__ xwf)
{
  int idx = blockIdx.x * 256 + threadIdx.x;
  if (idx >= 64 * 8 * 512) return;
  int strip = idx >> 12, rem = idx & 4095;
  int frag = rem >> 9, le = rem & 511;
  int lane = le >> 3, e = le & 7;
  int part = frag >> 2, ks = (frag >> 1) & 1, ni = frag & 1;
  int nt = strip >> 2, nh = strip & 3;
  int c = nt * 128 + nh * 32 + ni * 16 + (lane & 15);
  int k = ks * 32 + (lane >> 4) * 8 + e;
  int n = (c & 3) * 512 + (c >> 2);
  float w = Wih[n * 64 + k];
  u16 h = f2bf_rne(w);
  xwf[idx] = part ? f2bf_rne(w - bf2f(h)) : h;
}

__global__ __launch_bounds__(256) void pack_bias(const float* __restrict__ bih,
                                                 const float* __restrict__ bhh,
                                                 float* __restrict__ bias_pk)
{
  int c = blockIdx.x * 256 + threadIdx.x;
  if (c >= 2048) return;
  int n = (c & 3) * 512 + (c >> 2);
  bias_pk[c] = bih[n] + bhh[n];
}

__global__ __launch_bounds__(256) void transpose_wd(const float* __restrict__ Wd,
                                                    float* __restrict__ WdT)
{
  int idx = blockIdx.x * 256 + threadIdx.x;
  if (idx >= I_ * H_) return;
  int n = idx >> 9, k = idx & 511;
  WdT[k * 64 + n] = Wd[idx];
}

// x -> hi/lo bf16 fragment layout: xf[(t*128+rb)*2048 + (part*2+kf)*512 + lane*8]
__global__ __launch_bounds__(64) void prefrag_x(const float* __restrict__ x,
                                                u16* __restrict__ xf)
{
  int wg = blockIdx.x;
  int t = wg >> 7, rb = wg & 127;
  int l = threadIdx.x;
  __shared__ float tile[16][65];
  #pragma unroll
  for (int row = 0; row < 16; ++row)
    tile[row][l] = x[(((size_t)(rb * 16 + row)) * 256 + t) * 64 + l];
  __syncthreads();
  int lr = l & 15, lgp = l >> 4;
  size_t base = ((size_t)t * 128 + rb) * 2048;
  #pragma unroll
  for (int kf = 0; kf < 2; ++kf) {
    u32 hw[4], lw[4];
    #pragma unroll
    for (int e2 = 0; e2 < 4; ++e2) {
      float f0 = tile[lr][kf * 32 + lgp * 8 + e2 * 2];
      float f1 = tile[lr][kf * 32 + lgp * 8 + e2 * 2 + 1];
      u16 h0 = f2bf_rne(f0), h1 = f2bf_rne(f1);
      u16 l0 = f2bf_rne(f0 - bf2f(h0)), l1 = f2bf_rne(f1 - bf2f(h1));
      hw[e2] = (u32)h0 | ((u32)h1 << 16);
      lw[e2] = (u32)l0 | ((u32)l1 << 16);
    }
    *(uint4*)(xf + base + (0 * 2 + kf) * 512 + l * 8) = make_uint4(hw[0], hw[1], hw[2], hw[3]);
    *(uint4*)(xf + base + (1 * 2 + kf) * 512 + l * 8) = make_uint4(lw[0], lw[1], lw[2], lw[3]);
  }
}

// ---------------------------------------------------------------------------
__device__ __forceinline__ void stage_whh(const u16* src, char* smem, int tid){
  #pragma unroll
  for (int it = 0; it < 16; ++it)
    gl_lds16(src + it * 4096 + tid * 8, smem + it * 8192 + tid * 16);
}

__device__ __forceinline__ void load_xw(const u16* basep, int lane,
                                        bf16x8 whiR[2][2], bf16x8 wloR[2][2]){
  #pragma unroll
  for (int part = 0; part < 2; ++part)
    #pragma unroll
    for (int ks = 0; ks < 2; ++ks)
      #pragma unroll
      for (int ni = 0; ni < 2; ++ni) {
        bf16x8 v = ld_bf8(basep + ((part * 2 + ks) * 2 + ni) * 512 + lane * 8);
        if (part == 0) whiR[ks][ni] = v; else wloR[ks][ni] = v;
      }
}

__device__ __forceinline__ void gbar(u32* cptr, int& ev){
  __threadfence();
  __syncthreads();
  ++ev;
  if (threadIdx.x == 0) {
    __hip_atomic_fetch_add(cptr, 1u, __ATOMIC_RELEASE, __HIP_MEMORY_SCOPE_AGENT);
    u32 target = (u32)(ev * 16);
    while (__hip_atomic_load(cptr, __ATOMIC_ACQUIRE, __HIP_MEMORY_SCOPE_AGENT) < target)
      __builtin_amdgcn_s_sleep(1);
  }
  __syncthreads();
}

// ---------------------------------------------------------------------------
__global__ __launch_bounds__(512, 1) void lstm_persistent(
    const float* __restrict__ x, const u16* __restrict__ xf, int use_xf,
    const u16* __restrict__ WhhE, const u16* __restrict__ WhhD,
    const u16* __restrict__ xwE, const u16* __restrict__ xwD,
    const float* __restrict__ biasE, const float* __restrict__ biasD,
    u16* __restrict__ hb0, u16* __restrict__ hb1,
    float* __restrict__ hf32, float* __restrict__ dout,
    const float* __restrict__ WdT, const float* __restrict__ ldb,
    const float* __restrict__ loW, const float* __restrict__ lob,
    float* __restrict__ out, u32* __restrict__ cnt)
{
  extern __shared__ char smem[];
  const int tid = threadIdx.x;
  const int bid = blockIdx.x;
  const int mt = ((bid & 7) << 1) | ((bid >> 3) & 1);  // group members share XCD
  const int nt = bid >> 4;
  const int wid = tid >> 6, lane = tid & 63;
  const int mh = wid >> 2, nh = wid & 3;
  const int lr = lane & 15, lgp = lane >> 4;
  u32* cptr = cnt + mt * 16;   // 64B-padded per-group counter

  stage_whh(WhhE + (size_t)nt * WIMG2, smem, tid);
  bf16x8 whiR[2][2], wloR[2][2];
  load_xw(xwE + (size_t)(nt * 4 + nh) * 8 * 512, lane, whiR, wloR);
  f32x4 bvec[2];
  bvec[0] = *(const f32x4*)(biasE + nt * 128 + nh * 32 + lgp * 4);
  bvec[1] = *(const f32x4*)(biasE + nt * 128 + nh * 32 + 16 + lgp * 4);
  asm volatile("s_waitcnt vmcnt(0)" ::: "memory");
  __syncthreads();

  float creg[4][2];
  #pragma unroll
  for (int a = 0; a < 4; ++a) { creg[a][0] = 0.f; creg[a][1] = 0.f; }

  int ev = 0;
  for (int t = 0; t < TENC + TDEC; ++t) {
    if (t == TENC) {
      __syncthreads();   // all waves done reading encoder W image
      stage_whh(WhhD + (size_t)nt * WIMG2, smem, tid);
      load_xw(xwD + (size_t)(nt * 4 + nh) * 8 * 512, lane, whiR, wloR);
      bvec[0] = *(const f32x4*)(biasD + nt * 128 + nh * 32 + lgp * 4);
      bvec[1] = *(const f32x4*)(biasD + nt * 128 + nh * 32 + 16 + lgp * 4);
      asm volatile("s_waitcnt vmcnt(0)" ::: "memory");
      __syncthreads();
    }
    const u16* __restrict__ h_in  = (t & 1) ? hb1 : hb0;  // fragment layout
    u16*       __restrict__ h_out = (t & 1) ? hb0 : hb1;

    f32x4 acc[4][2];
    #pragma unroll
    for (int a = 0; a < 4; ++a) {
      acc[a][0] = (f32x4){0.f, 0.f, 0.f, 0.f};
      acc[a][1] = (f32x4){0.f, 0.f, 0.f, 0.f};
    }

    // ---- x phase (independent of h): load frags + MFMA BEFORE the barrier ----
    if (use_xf && t <= TENC) {
      int tx = (t < TENC) ? t : 255;
      #pragma unroll
      for (int mi = 0; mi < 4; ++mi) {
        const u16* fb = xf + ((size_t)tx * 128 + mt * 8 + mh * 4 + mi) * 2048;
        bf16x8 x0 = ld_bf8(fb +        lane * 8);
        bf16x8 x1 = ld_bf8(fb +  512 + lane * 8);
        bf16x8 l0 = ld_bf8(fb + 1024 + lane * 8);
        bf16x8 l1 = ld_bf8(fb + 1536 + lane * 8);
        #pragma unroll
        for (int ni = 0; ni < 2; ++ni) {
          acc[mi][ni] = MFMA16(whiR[0][ni], x0, acc[mi][ni], 0, 0, 0);
          acc[mi][ni] = MFMA16(wloR[0][ni], x0, acc[mi][ni], 0, 0, 0);
          acc[mi][ni] = MFMA16(whiR[1][ni], x1, acc[mi][ni], 0, 0, 0);
          acc[mi][ni] = MFMA16(wloR[1][ni], x1, acc[mi][ni], 0, 0, 0);
          acc[mi][ni] = MFMA16(whiR[0][ni], l0, acc[mi][ni], 0, 0, 0);
          acc[mi][ni] = MFMA16(whiR[1][ni], l1, acc[mi][ni], 0, 0, 0);
        }
      }
    } else {
      #pragma unroll
      for (int mi = 0; mi < 4; ++mi) {
        int brow = mt * 128 + mh * 64 + mi * 16 + lr;
        const float* p = (t > TENC) ? (dout + (size_t)brow * 64)
                                    : (x + ((size_t)brow * 256 + ((t < TENC) ? t : 255)) * 64);
        bf16x8 x0, x1, l0, l1;
        cvt_x8(p + lgp * 8,      x0, l0);
        cvt_x8(p + 32 + lgp * 8, x1, l1);
        #pragma unroll
        for (int ni = 0; ni < 2; ++ni) {
          acc[mi][ni] = MFMA16(whiR[0][ni], x0, acc[mi][ni], 0, 0, 0);
          acc[mi][ni] = MFMA16(wloR[0][ni], x0, acc[mi][ni], 0, 0, 0);
          acc[mi][ni] = MFMA16(whiR[1][ni], x1, acc[mi][ni], 0, 0, 0);
          acc[mi][ni] = MFMA16(wloR[1][ni], x1, acc[mi][ni], 0, 0, 0);
          acc[mi][ni] = MFMA16(whiR[0][ni], l0, acc[mi][ni], 0, 0, 0);
          acc[mi][ni] = MFMA16(whiR[1][ni], l1, acc[mi][ni], 0, 0, 0);
        }
      }
    }

    gbar(cptr, ev);   // h(t-1) fragments visible group-wide

    // ---- h phase: frag loads straight from global (coalesced 16B/lane),
    //      W-frags from resident LDS; no barriers, compiler schedules ----
    #pragma unroll 2
    for (int kb = 0; kb < 8; ++kb) {
      #pragma unroll
      for (int ks = 0; ks < 2; ++ks) {
        bf16x8 hfr[4], wf[2];
        #pragma unroll
        for (int mi = 0; mi < 4; ++mi)
          hfr[mi] = ld_bf8(h_in + (size_t)(mt * 8 + mh * 4 + mi) * 8192
                                 + (kb * 8 + ks * 4) * 128 + lane * 8);
        #pragma unroll
        for (int ni = 0; ni < 2; ++ni) {
          int crow = nh * 32 + ni * 16 + lr;
          wf[ni] = *(const bf16x8*)(smem + kb * 16384 + crow * 128 +
                                    (((ks * 4 + lgp) ^ (crow & 7)) << 4));
        }
        #pragma unroll
        for (int mi = 0; mi < 4; ++mi)
          #pragma unroll
          for (int ni = 0; ni < 2; ++ni)
            acc[mi][ni] = MFMA16(wf[ni], hfr[mi], acc[mi][ni], 0, 0, 0);
      }
    }

    // ---- fused LSTM epilogue; h written back in fragment layout ----
    #pragma unroll
    for (int mi = 0; mi < 4; ++mi)
      #pragma unroll
      for (int ni = 0; ni < 2; ++ni) {
        f32x4 g = acc[mi][ni];
        float gi = g[0] + bvec[ni][0];
        float gf = g[1] + bvec[ni][1];
        float gg = g[2] + bvec[ni][2];
        float go = g[3] + bvec[ni][3];
        float c0 = creg[mi][ni];
        float cn = sigm(gf) * c0 + sigm(gi) * tanhfast(gg);
        float hn = sigm(go) * tanhfast(cn);
        creg[mi][ni] = cn;
        int rowblk = mt * 8 + mh * 4 + mi;
        size_t off = (((size_t)rowblk * 64 + nt * 4 + nh) * 16 + lr) * 8 + ni * 4 + lgp;
        h_out[off] = f2bf_rne(hn);
        if (t >= TENC) {
          int brow = rowblk * 16 + lr;
          int j = nt * 32 + nh * 8 + ni * 4 + lgp;
          hf32[(size_t)brow * 512 + j] = hn;
        }
      }

    // ---- decoder projections ----
    if (t >= TENC) {
      gbar(cptr, ev);   // hf32 visible
      int d = t - TENC;
      int b = mt * 128 + nt * 8 + wid;
      const float* hr = hf32 + (size_t)b * 512;
      float a2 = ldb[lane];
      #pragma unroll 4
      for (int k = 0; k < 512; k += 4) {
        float4 hv = *(const float4*)(hr + k);
        a2 += hv.x * WdT[k * 64 + lane] + hv.y * WdT[(k + 1) * 64 + lane]
            + hv.z * WdT[(k + 2) * 64 + lane] + hv.w * WdT[(k + 3) * 64 + lane];
      }
      dout[(size_t)b * 64 + lane] = a2;
      float yv = a2 * loW[lane];
      #pragma unroll
      for (int off2 = 32; off2; off2 >>= 1) yv += __shfl_xor(yv, off2, 64);
      if (lane == 0) out[(size_t)b * TDEC + d] = yv + lob[0];
      if (t < TENC + TDEC - 1) gbar(cptr, ev);   // dout visible for next x
    }
  }
}

// ---------------------------------------------------------------------------
extern "C" void kernel_launch(void* const* d_in, const int* in_sizes, int n_in,
                              void* d_out, int out_size, void* d_ws, size_t ws_size,
                              hipStream_t stream)
{
  const float* x    = (const float*)d_in[0];
  const float* eWih = (const float*)d_in[1];
  const float* eWhh = (const float*)d_in[2];
  const float* ebih = (const float*)d_in[3];
  const float* ebhh = (const float*)d_in[4];
  const float* dWih = (const float*)d_in[5];
  const float* dWhh = (const float*)d_in[6];
  const float* dbih = (const float*)d_in[7];
  const float* dbhh = (const float*)d_in[8];
  const float* ldW  = (const float*)d_in[9];
  const float* ldbp = (const float*)d_in[10];
  const float* loW  = (const float*)d_in[11];
  const float* lob  = (const float*)d_in[12];
  float* out = (float*)d_out;

  char* ws = (char*)d_ws;
  size_t o = 0;
  auto alloc = [&](size_t bytes){ size_t r = o; o += (bytes + 255) & ~(size_t)255; return r; };
  u16*   WhhIE = (u16*)  (ws + alloc((size_t)16 * WIMG2 * 2));
  u16*   WhhID = (u16*)  (ws + alloc((size_t)16 * WIMG2 * 2));
  u16*   xwE   = (u16*)  (ws + alloc((size_t)64 * 8 * 512 * 2));
  u16*   xwD   = (u16*)  (ws + alloc((size_t)64 * 8 * 512 * 2));
  float* biasE = (float*)(ws + alloc(2048 * 4));
  float* biasD = (float*)(ws + alloc(2048 * 4));
  float* WdT   = (float*)(ws + alloc((size_t)I_ * H_ * 4));
  u16*   hb0   = (u16*)  (ws + alloc((size_t)B_ * H_ * 2));   // frag layout
  u16*   hb1   = (u16*)  (ws + alloc((size_t)B_ * H_ * 2));
  float* hf32  = (float*)(ws + alloc((size_t)B_ * H_ * 4));
  float* dout  = (float*)(ws + alloc((size_t)B_ * I_ * 4));
  u32*   cnt   = (u32*)  (ws + alloc(16 * 64));
  size_t xf_off = alloc((size_t)256 * 128 * 2048 * 2);   // 128 MiB
  int use_xf = (o <= ws_size) ? 1 : 0;
  u16* xf = use_xf ? (u16*)(ws + xf_off) : (u16*)(ws);
  (void)in_sizes; (void)n_in; (void)out_size;

  pack_whh<<<(16 * WIMG2 + 255) / 256, 256, 0, stream>>>(eWhh, WhhIE);
  pack_whh<<<(16 * WIMG2 + 255) / 256, 256, 0, stream>>>(dWhh, WhhID);
  pack_xw<<<(64 * 8 * 512 + 255) / 256, 256, 0, stream>>>(eWih, xwE);
  pack_xw<<<(64 * 8 * 512 + 255) / 256, 256, 0, stream>>>(dWih, xwD);
  pack_bias<<<8, 256, 0, stream>>>(ebih, ebhh, biasE);
  pack_bias<<<8, 256, 0, stream>>>(dbih, dbhh, biasD);
  transpose_wd<<<(I_ * H_ + 255) / 256, 256, 0, stream>>>(ldW, WdT);
  if (use_xf)
    prefrag_x<<<256 * 128, 64, 0, stream>>>(x, xf);
  hipMemsetAsync(hb0, 0, (size_t)B_ * H_ * 2, stream);
  hipMemsetAsync(cnt, 0, 16 * 64, stream);

  static bool attr_set = false;
  if (!attr_set) {
    hipFuncSetAttribute((const void*)lstm_persistent,
                        hipFuncAttributeMaxDynamicSharedMemorySize, 131072);
    attr_set = true;
  }

  const float* xp = x; const u16* xfp = xf; int uxf = use_xf;
  const u16 *we = WhhIE, *wd = WhhID, *xe = xwE, *xd = xwD;
  const float *be = biasE, *bd = biasD, *wdt = WdT, *lb = ldbp, *lw = loW, *lo2 = lob;
  u16 *h0 = hb0, *h1 = hb1;
  float *hf = hf32, *dp = dout, *op = out;
  u32* cp = cnt;
  void* kargs[] = { (void*)&xp, (void*)&xfp, (void*)&uxf, (void*)&we, (void*)&wd,
                    (void*)&xe, (void*)&xd, (void*)&be, (void*)&bd,
                    (void*)&h0, (void*)&h1, (void*)&hf, (void*)&dp, (void*)&wdt,
                    (void*)&lb, (void*)&lw, (void*)&lo2, (void*)&op, (void*)&cp };
  hipError_t e = hipLaunchCooperativeKernel((const void*)lstm_persistent,
                                            dim3(256), dim3(512), kargs, 131072, stream);
  if (e != hipSuccess) {
    lstm_persistent<<<256, 512, 131072, stream>>>(xp, xfp, uxf, we, wd, xe, xd,
                                                  be, bd, h0, h1, hf, dp, wdt,
                                                  lb, lw, lo2, op, cp);
  }
}

// Round 6
// 6141.973 us; speedup vs baseline: 3.1827x; 2.0737x over previous
//
#include <hip/hip_runtime.h>
#include <hip/hip_bf16.h>
#include <cstdint>

// Seq2Seq LSTM: B=2048, H=512, I=64, T_enc=256, T_dec=10.
// Persistent kernel, 256 WGs x 512 threads, 16 groups x 16 WGs.
// Inter-WG h exchange via explicit sc0+sc1 (MALL-coherent) asm loads/stores;
// group barrier = RELAXED atomics only (no L2 writeback/invalidate storms).
// Whh resident in LDS (128KB); x pre-fragmented hi/lo bf16; c in registers.

#define B_    2048
#define H_    512
#define I_    64
#define TENC  256
#define TDEC  10
#define WIMG2 65536   // u16 per nt Whh image: 8 blk * 128 row * 64 col

typedef __bf16 bf16x8 __attribute__((ext_vector_type(8)));
typedef float  f32x4  __attribute__((ext_vector_type(4)));
typedef unsigned int u32x4 __attribute__((ext_vector_type(4)));
typedef unsigned int   u32;
typedef unsigned short u16;

union BCV { uint4 u; bf16x8 b; };
union U4B { u32x4 u; bf16x8 b; f32x4 f; };

__device__ __forceinline__ u16 f2bf_rne(float f){
  u32 b = __float_as_uint(f);
  b += 0x7FFFu + ((b >> 16) & 1u);
  return (u16)(b >> 16);
}
__device__ __forceinline__ float bf2f(u16 u){ return __uint_as_float(((u32)u) << 16); }

__device__ __forceinline__ void gl_lds16(const void* g, void* l){
  __builtin_amdgcn_global_load_lds((const __attribute__((address_space(1))) u32*)g,
                                   (__attribute__((address_space(3))) u32*)l, 16, 0, 0);
}

__device__ __forceinline__ float sigm(float x){ return 1.f / (1.f + __expf(-x)); }
__device__ __forceinline__ float tanhfast(float x){ return 1.f - 2.f / (1.f + __expf(2.f * x)); }

#define MFMA16 __builtin_amdgcn_mfma_f32_16x16x32_bf16

// device-coherent (MALL) 16B load / 4B store, bypassing L1+L2
#define HLD(dst, ptr) \
  asm volatile("global_load_dwordx4 %0, %1, off sc0 sc1" : "=v"(dst) : "v"(ptr))
#define HST32(ptr, val) \
  asm volatile("global_store_dword %0, %1, off sc0 sc1" :: "v"(ptr), "v"(val) : "memory")

__device__ __forceinline__ bf16x8 ld_bf8(const u16* p){
  BCV cv; cv.u = *(const uint4*)p; return cv.b;
}

// 8 floats -> hi/lo bf16x8 fragments
__device__ __forceinline__ void cvt8(const float* f, bf16x8& hi, bf16x8& lo){
  u32 hw[4], lw[4];
  #pragma unroll
  for (int e = 0; e < 4; ++e) {
    float f0 = f[e*2], f1 = f[e*2+1];
    u16 h0 = f2bf_rne(f0), h1 = f2bf_rne(f1);
    u16 l0 = f2bf_rne(f0 - bf2f(h0)), l1 = f2bf_rne(f1 - bf2f(h1));
    hw[e] = (u32)h0 | ((u32)h1 << 16);
    lw[e] = (u32)l0 | ((u32)l1 << 16);
  }
  BCV ch, cl;
  ch.u = make_uint4(hw[0], hw[1], hw[2], hw[3]);
  cl.u = make_uint4(lw[0], lw[1], lw[2], lw[3]);
  hi = ch.b; lo = cl.b;
}

// ---------------------------------------------------------------------------
// Packed-col -> original-row map. c in [0,2048): cl=c&127, nt=c>>7.
// gate = cl&3; u = nt*32 + ((cl>>5)&3)*8 + ((cl>>2)&3)*2 + ((cl>>4)&1).
// n = gate*512 + u.  (Matches epilogue j = nt*32+nh*8+lgp*2+ni, e=lgp*2+ni.)
// ---------------------------------------------------------------------------
__device__ __forceinline__ int colmap(int c){
  int cl = c & 127, nt = c >> 7;
  return (cl & 3) * 512 + nt * 32 + ((cl >> 5) & 3) * 8 + ((cl >> 2) & 3) * 2 + ((cl >> 4) & 1);
}

__global__ __launch_bounds__(256) void pack_whh(const float* __restrict__ Whh,
                                                u16* __restrict__ img)
{
  int idx = blockIdx.x * 256 + threadIdx.x;
  if (idx >= 16 * WIMG2) return;
  int nt = idx >> 16, rem = idx & 65535;
  int blk = rem >> 13, r2 = rem & 8191;
  int row = r2 >> 6, col = r2 & 63;
  int sc = col >> 3, e = col & 7;
  int lc = ((sc ^ (row & 7)) << 3) + e;
  int n = colmap(nt * 128 + row);
  img[idx] = f2bf_rne(Whh[(size_t)n * 512 + blk * 64 + lc]);
}

__global__ __launch_bounds__(256) void pack_xw(const float* __restrict__ Wih,
                                               u16* __restrict__ xwf)
{
  int idx = blockIdx.x * 256 + threadIdx.x;
  if (idx >= 64 * 8 * 512) return;
  int strip = idx >> 12, rem = idx & 4095;
  int frag = rem >> 9, le = rem & 511;
  int lane = le >> 3, e = le & 7;
  int part = frag >> 2, ks = (frag >> 1) & 1, ni = frag & 1;
  int nt = strip >> 2, nh = strip & 3;
  int c = nt * 128 + nh * 32 + ni * 16 + (lane & 15);
  int k = ks * 32 + (lane >> 4) * 8 + e;
  int n = colmap(c);
  float w = Wih[n * 64 + k];
  u16 h = f2bf_rne(w);
  xwf[idx] = part ? f2bf_rne(w - bf2f(h)) : h;
}

__global__ __launch_bounds__(256) void pack_bias(const float* __restrict__ bih,
                                                 const float* __restrict__ bhh,
                                                 float* __restrict__ bias_pk)
{
  int c = blockIdx.x * 256 + threadIdx.x;
  if (c >= 2048) return;
  int n = colmap(c);
  bias_pk[c] = bih[n] + bhh[n];
}

__global__ __launch_bounds__(256) void transpose_wd(const float* __restrict__ Wd,
                                                    float* __restrict__ WdT)
{
  int idx = blockIdx.x * 256 + threadIdx.x;
  if (idx >= I_ * H_) return;
  int n = idx >> 9, k = idx & 511;
  WdT[k * 64 + n] = Wd[idx];
}

// x -> hi/lo bf16 fragment layout: xf[(t*128+rb)*2048 + (part*2+kf)*512 + lane*8]
__global__ __launch_bounds__(64) void prefrag_x(const float* __restrict__ x,
                                                u16* __restrict__ xf)
{
  int wg = blockIdx.x;
  int t = wg >> 7, rb = wg & 127;
  int l = threadIdx.x;
  __shared__ float tile[16][65];
  #pragma unroll
  for (int row = 0; row < 16; ++row)
    tile[row][l] = x[(((size_t)(rb * 16 + row)) * 256 + t) * 64 + l];
  __syncthreads();
  int lr = l & 15, lgp = l >> 4;
  size_t base = ((size_t)t * 128 + rb) * 2048;
  #pragma unroll
  for (int kf = 0; kf < 2; ++kf) {
    float fv[8];
    #pragma unroll
    for (int e2 = 0; e2 < 8; ++e2) fv[e2] = tile[lr][kf * 32 + lgp * 8 + e2];
    bf16x8 hi, lo;
    cvt8(fv, hi, lo);
    BCV ch, cl; ch.b = hi; cl.b = lo;
    *(uint4*)(xf + base + (0 * 2 + kf) * 512 + l * 8) = ch.u;
    *(uint4*)(xf + base + (1 * 2 + kf) * 512 + l * 8) = cl.u;
  }
}

// ---------------------------------------------------------------------------
__device__ __forceinline__ void stage_whh(const u16* src, char* smem, int tid){
  #pragma unroll
  for (int it = 0; it < 16; ++it)
    gl_lds16(src + it * 4096 + tid * 8, smem + it * 8192 + tid * 16);
}

__device__ __forceinline__ void load_xw(const u16* basep, int lane,
                                        bf16x8 whiR[2][2], bf16x8 wloR[2][2]){
  #pragma unroll
  for (int part = 0; part < 2; ++part)
    #pragma unroll
    for (int ks = 0; ks < 2; ++ks)
      #pragma unroll
      for (int ni = 0; ni < 2; ++ni) {
        bf16x8 v = ld_bf8(basep + ((part * 2 + ks) * 2 + ni) * 512 + lane * 8);
        if (part == 0) whiR[ks][ni] = v; else wloR[ks][ni] = v;
      }
}

// Relaxed group barrier: no acquire/release cache ops. Release = vmcnt(0)
// before the increment (stores ack'd at the coherent point); data is read
// with sc0sc1 so no invalidation is needed on the acquire side.
__device__ __forceinline__ void gbar(u32* cptr, int& ev){
  asm volatile("s_waitcnt vmcnt(0)" ::: "memory");
  __syncthreads();
  ++ev;
  if (threadIdx.x == 0) {
    __hip_atomic_fetch_add(cptr, 1u, __ATOMIC_RELAXED, __HIP_MEMORY_SCOPE_AGENT);
    while (__hip_atomic_load(cptr, __ATOMIC_RELAXED, __HIP_MEMORY_SCOPE_AGENT) < (u32)(ev * 16))
      __builtin_amdgcn_s_sleep(2);
  }
  __syncthreads();
}

// issue one K-block's 8 h-fragment loads (16B/lane, coalesced, sc0sc1)
__device__ __forceinline__ void issue_h(const u16* h_in, int rbase, int lane,
                                        int kb, U4B (&dst)[8]){
  #pragma unroll
  for (int ks = 0; ks < 2; ++ks)
    #pragma unroll
    for (int mi = 0; mi < 4; ++mi) {
      const u16* p = h_in + (size_t)(rbase + mi) * 8192 + (kb * 2 + ks) * 512
                     + (lane >> 4) * 128 + (lane & 15) * 8;
      HLD(dst[ks * 4 + mi].u, p);
    }
}

// ---------------------------------------------------------------------------
__global__ __launch_bounds__(512, 1) void lstm_persistent(
    const float* __restrict__ x, const u16* __restrict__ xf, int use_xf,
    const u16* __restrict__ WhhE, const u16* __restrict__ WhhD,
    const u16* __restrict__ xwE, const u16* __restrict__ xwD,
    const float* __restrict__ biasE, const float* __restrict__ biasD,
    u16* __restrict__ hb0, u16* __restrict__ hb1,
    float* __restrict__ dout,
    const float* __restrict__ WdT, const float* __restrict__ ldb,
    const float* __restrict__ loW, const float* __restrict__ lob,
    float* __restrict__ out, u32* __restrict__ cnt)
{
  extern __shared__ char smem[];
  const int tid = threadIdx.x;
  const int bid = blockIdx.x;
  const int mt = ((bid & 7) << 1) | ((bid >> 3) & 1);
  const int nt = bid >> 4;
  const int wid = tid >> 6, lane = tid & 63;
  const int mh = wid >> 2, nh = wid & 3;
  const int lr = lane & 15, lgp = lane >> 4;
  u32* cptr = cnt + mt * 16;

  stage_whh(WhhE + (size_t)nt * WIMG2, smem, tid);
  bf16x8 whiR[2][2], wloR[2][2];
  load_xw(xwE + (size_t)(nt * 4 + nh) * 8 * 512, lane, whiR, wloR);
  f32x4 bvec[2];
  bvec[0] = *(const f32x4*)(biasE + nt * 128 + nh * 32 + lgp * 4);
  bvec[1] = *(const f32x4*)(biasE + nt * 128 + nh * 32 + 16 + lgp * 4);
  asm volatile("s_waitcnt vmcnt(0)" ::: "memory");
  __syncthreads();

  float creg[4][2];
  #pragma unroll
  for (int a = 0; a < 4; ++a) { creg[a][0] = 0.f; creg[a][1] = 0.f; }

  const int rbase = mt * 8 + mh * 4;
  int ev = 0;

  for (int t = 0; t < TENC + TDEC; ++t) {
    if (t == TENC) {
      __syncthreads();
      stage_whh(WhhD + (size_t)nt * WIMG2, smem, tid);
      load_xw(xwD + (size_t)(nt * 4 + nh) * 8 * 512, lane, whiR, wloR);
      bvec[0] = *(const f32x4*)(biasD + nt * 128 + nh * 32 + lgp * 4);
      bvec[1] = *(const f32x4*)(biasD + nt * 128 + nh * 32 + 16 + lgp * 4);
      asm volatile("s_waitcnt vmcnt(0)" ::: "memory");
      __syncthreads();
    }
    const u16* __restrict__ h_in  = (t & 1) ? hb1 : hb0;
    u16*       __restrict__ h_out = (t & 1) ? hb0 : hb1;

    f32x4 acc[4][2];
    #pragma unroll
    for (int a = 0; a < 4; ++a) {
      acc[a][0] = (f32x4){0.f, 0.f, 0.f, 0.f};
      acc[a][1] = (f32x4){0.f, 0.f, 0.f, 0.f};
    }

    // ---- x phase (independent of h): BEFORE the group barrier ----
    if (t > TENC) {
      // x = dout (written sc0sc1 by siblings last step): coherent asm loads
      U4B db[4][4];
      #pragma unroll
      for (int mi = 0; mi < 4; ++mi) {
        const float* p = dout + (size_t)(mt * 128 + mh * 64 + mi * 16 + lr) * 64 + lgp * 8;
        HLD(db[mi][0].u, p); HLD(db[mi][1].u, p + 4);
        HLD(db[mi][2].u, p + 32); HLD(db[mi][3].u, p + 36);
      }
      asm volatile("s_waitcnt vmcnt(0)" ::: "memory");
      __builtin_amdgcn_sched_barrier(0);
      #pragma unroll
      for (int mi = 0; mi < 4; ++mi) {
        #pragma unroll
        for (int ks = 0; ks < 2; ++ks) {
          float fv[8];
          #pragma unroll
          for (int e = 0; e < 4; ++e) {
            fv[e]     = db[mi][ks*2].f[e];
            fv[4 + e] = db[mi][ks*2 + 1].f[e];
          }
          bf16x8 xh, xl;
          cvt8(fv, xh, xl);
          #pragma unroll
          for (int ni = 0; ni < 2; ++ni) {
            acc[mi][ni] = MFMA16(whiR[ks][ni], xh, acc[mi][ni], 0, 0, 0);
            acc[mi][ni] = MFMA16(wloR[ks][ni], xh, acc[mi][ni], 0, 0, 0);
            acc[mi][ni] = MFMA16(whiR[ks][ni], xl, acc[mi][ni], 0, 0, 0);
          }
        }
      }
    } else if (use_xf) {
      int tx = (t < TENC) ? t : 255;
      #pragma unroll
      for (int mi = 0; mi < 4; ++mi) {
        const u16* fb = xf + ((size_t)tx * 128 + rbase + mi) * 2048;
        bf16x8 x0 = ld_bf8(fb +        lane * 8);
        bf16x8 x1 = ld_bf8(fb +  512 + lane * 8);
        bf16x8 l0 = ld_bf8(fb + 1024 + lane * 8);
        bf16x8 l1 = ld_bf8(fb + 1536 + lane * 8);
        #pragma unroll
        for (int ni = 0; ni < 2; ++ni) {
          acc[mi][ni] = MFMA16(whiR[0][ni], x0, acc[mi][ni], 0, 0, 0);
          acc[mi][ni] = MFMA16(wloR[0][ni], x0, acc[mi][ni], 0, 0, 0);
          acc[mi][ni] = MFMA16(whiR[1][ni], x1, acc[mi][ni], 0, 0, 0);
          acc[mi][ni] = MFMA16(wloR[1][ni], x1, acc[mi][ni], 0, 0, 0);
          acc[mi][ni] = MFMA16(whiR[0][ni], l0, acc[mi][ni], 0, 0, 0);
          acc[mi][ni] = MFMA16(whiR[1][ni], l1, acc[mi][ni], 0, 0, 0);
        }
      }
    } else {
      #pragma unroll
      for (int mi = 0; mi < 4; ++mi) {
        int brow = mt * 128 + mh * 64 + mi * 16 + lr;
        const float* p = x + ((size_t)brow * 256 + ((t < TENC) ? t : 255)) * 64;
        float fv[8];
        #pragma unroll
        for (int ks = 0; ks < 2; ++ks) {
          #pragma unroll
          for (int e = 0; e < 8; ++e) fv[e] = p[ks * 32 + lgp * 8 + e];
          bf16x8 xh, xl;
          cvt8(fv, xh, xl);
          #pragma unroll
          for (int ni = 0; ni < 2; ++ni) {
            acc[mi][ni] = MFMA16(whiR[ks][ni], xh, acc[mi][ni], 0, 0, 0);
            acc[mi][ni] = MFMA16(wloR[ks][ni], xh, acc[mi][ni], 0, 0, 0);
            acc[mi][ni] = MFMA16(whiR[ks][ni], xl, acc[mi][ni], 0, 0, 0);
          }
        }
      }
    }

    gbar(cptr, ev);   // h(t-1) stores from siblings ack'd at coherent point

    // ---- h phase: sc0sc1 frag loads, 2-deep pipeline, counted vmcnt ----
    {
      U4B hr[2][8];
      issue_h(h_in, rbase, lane, 0, hr[0]);
      #pragma unroll
      for (int kb = 0; kb < 8; ++kb) {
        if (kb < 7) issue_h(h_in, rbase, lane, kb + 1, hr[(kb + 1) & 1]);
        if (kb < 7) { asm volatile("s_waitcnt vmcnt(8)" ::: "memory"); }
        else        { asm volatile("s_waitcnt vmcnt(0)" ::: "memory"); }
        __builtin_amdgcn_sched_barrier(0);
        #pragma unroll
        for (int ks = 0; ks < 2; ++ks) {
          bf16x8 wf[2];
          #pragma unroll
          for (int ni = 0; ni < 2; ++ni) {
            int crow = nh * 32 + ni * 16 + lr;
            wf[ni] = *(const bf16x8*)(smem + kb * 16384 + crow * 128 +
                                      (((ks * 4 + lgp) ^ (crow & 7)) << 4));
          }
          #pragma unroll
          for (int mi = 0; mi < 4; ++mi)
            #pragma unroll
            for (int ni = 0; ni < 2; ++ni)
              acc[mi][ni] = MFMA16(wf[ni], hr[kb & 1][ks * 4 + mi].b, acc[mi][ni], 0, 0, 0);
        }
      }
    }

    // ---- fused LSTM epilogue; h packed 2x bf16 -> u32 sc0sc1 store ----
    #pragma unroll
    for (int mi = 0; mi < 4; ++mi) {
      float hn2[2];
      #pragma unroll
      for (int ni = 0; ni < 2; ++ni) {
        f32x4 g = acc[mi][ni];
        float gi = g[0] + bvec[ni][0];
        float gf = g[1] + bvec[ni][1];
        float gg = g[2] + bvec[ni][2];
        float go = g[3] + bvec[ni][3];
        float c0 = creg[mi][ni];
        float cn = sigm(gf) * c0 + sigm(gi) * tanhfast(gg);
        hn2[ni] = sigm(go) * tanhfast(cn);
        creg[mi][ni] = cn;
      }
      u32 pk = (u32)f2bf_rne(hn2[0]) | ((u32)f2bf_rne(hn2[1]) << 16);
      u16* p = h_out + (size_t)(rbase + mi) * 8192 + nt * 512 + nh * 128 + lr * 8 + lgp * 2;
      HST32(p, pk);
    }

    // ---- decoder projections (bf16 h, broadcast sc0sc1 chunk loads) ----
    if (t >= TENC) {
      gbar(cptr, ev);   // h(t) complete group-wide
      int d = t - TENC;
      int b = mt * 128 + nt * 8 + wid;
      int rb = b >> 4, lrb = b & 15;
      const u16* hbase = h_out + (size_t)rb * 8192 + lrb * 8;
      float a2 = ldb[lane];
      #pragma unroll
      for (int g8 = 0; g8 < 8; ++g8) {
        U4B hc[8];
        #pragma unroll
        for (int q = 0; q < 8; ++q)
          HLD(hc[q].u, hbase + (g8 * 8 + q) * 128);
        asm volatile("s_waitcnt vmcnt(0)" ::: "memory");
        __builtin_amdgcn_sched_barrier(0);
        #pragma unroll
        for (int q = 0; q < 8; ++q) {
          #pragma unroll
          for (int e = 0; e < 8; ++e) {
            float hv = bf2f(((const u16*)&hc[q].u)[e]);
            a2 += hv * WdT[(g8 * 64 + q * 8 + e) * 64 + lane];
          }
        }
      }
      HST32((float*)(dout + (size_t)b * 64 + lane), a2);
      float yv = a2 * loW[lane];
      #pragma unroll
      for (int off2 = 32; off2; off2 >>= 1) yv += __shfl_xor(yv, off2, 64);
      if (lane == 0) out[(size_t)b * TDEC + d] = yv + lob[0];
      if (t < TENC + TDEC - 1) gbar(cptr, ev);   // dout visible for next x
    }
  }
}

// ---------------------------------------------------------------------------
extern "C" void kernel_launch(void* const* d_in, const int* in_sizes, int n_in,
                              void* d_out, int out_size, void* d_ws, size_t ws_size,
                              hipStream_t stream)
{
  const float* x    = (const float*)d_in[0];
  const float* eWih = (const float*)d_in[1];
  const float* eWhh = (const float*)d_in[2];
  const float* ebih = (const float*)d_in[3];
  const float* ebhh = (const float*)d_in[4];
  const float* dWih = (const float*)d_in[5];
  const float* dWhh = (const float*)d_in[6];
  const float* dbih = (const float*)d_in[7];
  const float* dbhh = (const float*)d_in[8];
  const float* ldW  = (const float*)d_in[9];
  const float* ldbp = (const float*)d_in[10];
  const float* loW  = (const float*)d_in[11];
  const float* lob  = (const float*)d_in[12];
  float* out = (float*)d_out;

  char* ws = (char*)d_ws;
  size_t o = 0;
  auto alloc = [&](size_t bytes){ size_t r = o; o += (bytes + 255) & ~(size_t)255; return r; };
  u16*   WhhIE = (u16*)  (ws + alloc((size_t)16 * WIMG2 * 2));
  u16*   WhhID = (u16*)  (ws + alloc((size_t)16 * WIMG2 * 2));
  u16*   xwE   = (u16*)  (ws + alloc((size_t)64 * 8 * 512 * 2));
  u16*   xwD   = (u16*)  (ws + alloc((size_t)64 * 8 * 512 * 2));
  float* biasE = (float*)(ws + alloc(2048 * 4));
  float* biasD = (float*)(ws + alloc(2048 * 4));
  float* WdT   = (float*)(ws + alloc((size_t)I_ * H_ * 4));
  u16*   hb0   = (u16*)  (ws + alloc((size_t)B_ * H_ * 2));
  u16*   hb1   = (u16*)  (ws + alloc((size_t)B_ * H_ * 2));
  float* dout  = (float*)(ws + alloc((size_t)B_ * I_ * 4));
  u32*   cnt   = (u32*)  (ws + alloc(16 * 64));
  size_t xf_off = alloc((size_t)256 * 128 * 2048 * 2);   // 128 MiB
  int use_xf = (o <= ws_size) ? 1 : 0;
  u16* xf = use_xf ? (u16*)(ws + xf_off) : (u16*)(ws);
  (void)in_sizes; (void)n_in; (void)out_size;

  pack_whh<<<(16 * WIMG2 + 255) / 256, 256, 0, stream>>>(eWhh, WhhIE);
  pack_whh<<<(16 * WIMG2 + 255) / 256, 256, 0, stream>>>(dWhh, WhhID);
  pack_xw<<<(64 * 8 * 512 + 255) / 256, 256, 0, stream>>>(eWih, xwE);
  pack_xw<<<(64 * 8 * 512 + 255) / 256, 256, 0, stream>>>(dWih, xwD);
  pack_bias<<<8, 256, 0, stream>>>(ebih, ebhh, biasE);
  pack_bias<<<8, 256, 0, stream>>>(dbih, dbhh, biasD);
  transpose_wd<<<(I_ * H_ + 255) / 256, 256, 0, stream>>>(ldW, WdT);
  if (use_xf)
    prefrag_x<<<256 * 128, 64, 0, stream>>>(x, xf);
  (void)hipMemsetAsync(hb0, 0, (size_t)B_ * H_ * 2, stream);
  (void)hipMemsetAsync(cnt, 0, 16 * 64, stream);

  static bool attr_set = false;
  if (!attr_set) {
    (void)hipFuncSetAttribute((const void*)lstm_persistent,
                              hipFuncAttributeMaxDynamicSharedMemorySize, 131072);
    attr_set = true;
  }

  const float* xp = x; const u16* xfp = xf; int uxf = use_xf;
  const u16 *we = WhhIE, *wd = WhhID, *xe = xwE, *xd = xwD;
  const float *be = biasE, *bd = biasD, *wdt = WdT, *lb = ldbp, *lw = loW, *lo2 = lob;
  u16 *h0 = hb0, *h1 = hb1;
  float *dp = dout, *op = out;
  u32* cp = cnt;
  void* kargs[] = { (void*)&xp, (void*)&xfp, (void*)&uxf, (void*)&we, (void*)&wd,
                    (void*)&xe, (void*)&xd, (void*)&be, (void*)&bd,
                    (void*)&h0, (void*)&h1, (void*)&dp, (void*)&wdt,
                    (void*)&lb, (void*)&lw, (void*)&lo2, (void*)&op, (void*)&cp };
  hipError_t e = hipLaunchCooperativeKernel((const void*)lstm_persistent,
                                            dim3(256), dim3(512), kargs, 131072, stream);
  if (e != hipSuccess) {
    lstm_persistent<<<256, 512, 131072, stream>>>(xp, xfp, uxf, we, wd, xe, xd,
                                                  be, bd, h0, h1, dp, wdt,
                                                  lb, lw, lo2, op, cp);
  }
}

// Round 7
// 3089.723 us; speedup vs baseline: 6.3268x; 1.9879x over previous
//
#include <hip/hip_runtime.h>
#include <hip/hip_bf16.h>
#include <cstdint>

// Seq2Seq LSTM: B=2048, H=512, I=64, T_enc=256, T_dec=10.
// Persistent kernel, 256 WGs x 512 threads, 16 groups x 16 WGs.
// h exchange: sc0sc1 write-through stores (device-coherent point) + NORMAL
// cached reads, made safe by ONE agent-acquire fence (buffer_inv) per WG per
// group barrier. Redundant reads are then served by L1 (x4 wave dedup) and
// XCD L2 (x16 group dedup) instead of hammering the MALL (round-6 bound).
// Whh resident in LDS (128KB); x pre-fragmented hi/lo bf16; c in registers.

#define B_    2048
#define H_    512
#define I_    64
#define TENC  256
#define TDEC  10
#define WIMG2 65536   // u16 per nt Whh image: 8 blk * 128 row * 64 col

typedef __bf16 bf16x8 __attribute__((ext_vector_type(8)));
typedef float  f32x4  __attribute__((ext_vector_type(4)));
typedef unsigned int u32x4 __attribute__((ext_vector_type(4)));
typedef unsigned int   u32;
typedef unsigned short u16;

union BCV { uint4 u; bf16x8 b; };
union U4B { u32x4 u; bf16x8 b; f32x4 f; };

__device__ __forceinline__ u16 f2bf_rne(float f){
  u32 b = __float_as_uint(f);
  b += 0x7FFFu + ((b >> 16) & 1u);
  return (u16)(b >> 16);
}
__device__ __forceinline__ float bf2f(u16 u){ return __uint_as_float(((u32)u) << 16); }

__device__ __forceinline__ void gl_lds16(const void* g, void* l){
  __builtin_amdgcn_global_load_lds((const __attribute__((address_space(1))) u32*)g,
                                   (__attribute__((address_space(3))) u32*)l, 16, 0, 0);
}

__device__ __forceinline__ float sigm(float x){ return 1.f / (1.f + __expf(-x)); }
__device__ __forceinline__ float tanhfast(float x){ return 1.f - 2.f / (1.f + __expf(2.f * x)); }

#define MFMA16 __builtin_amdgcn_mfma_f32_16x16x32_bf16

// cached 16B load (normal path: L1+L2), asm so manual vmcnt counting holds
#define GLD16(dst, ptr) \
  asm volatile("global_load_dwordx4 %0, %1, off" : "=v"(dst) : "v"(ptr))
// device-coherent (MALL) 4B write-through store
#define HST32(ptr, val) \
  asm volatile("global_store_dword %0, %1, off sc0 sc1" :: "v"(ptr), "v"(val) : "memory")

__device__ __forceinline__ bf16x8 ld_bf8(const u16* p){
  BCV cv; cv.u = *(const uint4*)p; return cv.b;
}

// 8 floats -> hi/lo bf16x8 fragments
__device__ __forceinline__ void cvt8(const float* f, bf16x8& hi, bf16x8& lo){
  u32 hw[4], lw[4];
  #pragma unroll
  for (int e = 0; e < 4; ++e) {
    float f0 = f[e*2], f1 = f[e*2+1];
    u16 h0 = f2bf_rne(f0), h1 = f2bf_rne(f1);
    u16 l0 = f2bf_rne(f0 - bf2f(h0)), l1 = f2bf_rne(f1 - bf2f(h1));
    hw[e] = (u32)h0 | ((u32)h1 << 16);
    lw[e] = (u32)l0 | ((u32)l1 << 16);
  }
  BCV ch, cl;
  ch.u = make_uint4(hw[0], hw[1], hw[2], hw[3]);
  cl.u = make_uint4(lw[0], lw[1], lw[2], lw[3]);
  hi = ch.b; lo = cl.b;
}

// ---------------------------------------------------------------------------
// Packed-col -> original-row map. c in [0,2048): cl=c&127, nt=c>>7.
// gate = cl&3; u = nt*32 + ((cl>>5)&3)*8 + ((cl>>2)&3)*2 + ((cl>>4)&1).
// ---------------------------------------------------------------------------
__device__ __forceinline__ int colmap(int c){
  int cl = c & 127, nt = c >> 7;
  return (cl & 3) * 512 + nt * 32 + ((cl >> 5) & 3) * 8 + ((cl >> 2) & 3) * 2 + ((cl >> 4) & 1);
}

__global__ __launch_bounds__(256) void pack_whh(const float* __restrict__ Whh,
                                                u16* __restrict__ img)
{
  int idx = blockIdx.x * 256 + threadIdx.x;
  if (idx >= 16 * WIMG2) return;
  int nt = idx >> 16, rem = idx & 65535;
  int blk = rem >> 13, r2 = rem & 8191;
  int row = r2 >> 6, col = r2 & 63;
  int sc = col >> 3, e = col & 7;
  int lc = ((sc ^ (row & 7)) << 3) + e;
  int n = colmap(nt * 128 + row);
  img[idx] = f2bf_rne(Whh[(size_t)n * 512 + blk * 64 + lc]);
}

__global__ __launch_bounds__(256) void pack_xw(const float* __restrict__ Wih,
                                               u16* __restrict__ xwf)
{
  int idx = blockIdx.x * 256 + threadIdx.x;
  if (idx >= 64 * 8 * 512) return;
  int strip = idx >> 12, rem = idx & 4095;
  int frag = rem >> 9, le = rem & 511;
  int lane = le >> 3, e = le & 7;
  int part = frag >> 2, ks = (frag >> 1) & 1, ni = frag & 1;
  int nt = strip >> 2, nh = strip & 3;
  int c = nt * 128 + nh * 32 + ni * 16 + (lane & 15);
  int k = ks * 32 + (lane >> 4) * 8 + e;
  int n = colmap(c);
  float w = Wih[n * 64 + k];
  u16 h = f2bf_rne(w);
  xwf[idx] = part ? f2bf_rne(w - bf2f(h)) : h;
}

__global__ __launch_bounds__(256) void pack_bias(const float* __restrict__ bih,
                                                 const float* __restrict__ bhh,
                                                 float* __restrict__ bias_pk)
{
  int c = blockIdx.x * 256 + threadIdx.x;
  if (c >= 2048) return;
  int n = colmap(c);
  bias_pk[c] = bih[n] + bhh[n];
}

__global__ __launch_bounds__(256) void transpose_wd(const float* __restrict__ Wd,
                                                    float* __restrict__ WdT)
{
  int idx = blockIdx.x * 256 + threadIdx.x;
  if (idx >= I_ * H_) return;
  int n = idx >> 9, k = idx & 511;
  WdT[k * 64 + n] = Wd[idx];
}

// x -> hi/lo bf16 fragment layout: xf[(t*128+rb)*2048 + (part*2+kf)*512 + lane*8]
__global__ __launch_bounds__(64) void prefrag_x(const float* __restrict__ x,
                                                u16* __restrict__ xf)
{
  int wg = blockIdx.x;
  int t = wg >> 7, rb = wg & 127;
  int l = threadIdx.x;
  __shared__ float tile[16][65];
  #pragma unroll
  for (int row = 0; row < 16; ++row)
    tile[row][l] = x[(((size_t)(rb * 16 + row)) * 256 + t) * 64 + l];
  __syncthreads();
  int lr = l & 15, lgp = l >> 4;
  size_t base = ((size_t)t * 128 + rb) * 2048;
  #pragma unroll
  for (int kf = 0; kf < 2; ++kf) {
    float fv[8];
    #pragma unroll
    for (int e2 = 0; e2 < 8; ++e2) fv[e2] = tile[lr][kf * 32 + lgp * 8 + e2];
    bf16x8 hi, lo;
    cvt8(fv, hi, lo);
    BCV ch, cl; ch.b = hi; cl.b = lo;
    *(uint4*)(xf + base + (0 * 2 + kf) * 512 + l * 8) = ch.u;
    *(uint4*)(xf + base + (1 * 2 + kf) * 512 + l * 8) = cl.u;
  }
}

// ---------------------------------------------------------------------------
__device__ __forceinline__ void stage_whh(const u16* src, char* smem, int tid){
  #pragma unroll
  for (int it = 0; it < 16; ++it)
    gl_lds16(src + it * 4096 + tid * 8, smem + it * 8192 + tid * 16);
}

__device__ __forceinline__ void load_xw(const u16* basep, int lane,
                                        bf16x8 whiR[2][2], bf16x8 wloR[2][2]){
  #pragma unroll
  for (int part = 0; part < 2; ++part)
    #pragma unroll
    for (int ks = 0; ks < 2; ++ks)
      #pragma unroll
      for (int ni = 0; ni < 2; ++ni) {
        bf16x8 v = ld_bf8(basep + ((part * 2 + ks) * 2 + ni) * 512 + lane * 8);
        if (part == 0) whiR[ks][ni] = v; else wloR[ks][ni] = v;
      }
}

// Group barrier. Release: vmcnt(0) (sc0sc1 stores ack'd at coherent point)
// + relaxed add. Acquire: relaxed poll, then ONE agent-acquire fence
// (buffer_inv) so subsequent NORMAL cached loads can't see stale L1/L2 lines.
__device__ __forceinline__ void gbar(u32* cptr, int& ev){
  asm volatile("s_waitcnt vmcnt(0)" ::: "memory");
  __syncthreads();
  ++ev;
  if (threadIdx.x == 0) {
    __hip_atomic_fetch_add(cptr, 1u, __ATOMIC_RELAXED, __HIP_MEMORY_SCOPE_AGENT);
    while (__hip_atomic_load(cptr, __ATOMIC_RELAXED, __HIP_MEMORY_SCOPE_AGENT) < (u32)(ev * 16))
      __builtin_amdgcn_s_sleep(2);
    __builtin_amdgcn_fence(__ATOMIC_ACQUIRE, "agent");
  }
  __syncthreads();
}

// issue one K-block's 8 h-fragment loads (16B/lane, coalesced, cached)
__device__ __forceinline__ void issue_h(const u16* h_in, int rbase, int lane,
                                        int kb, U4B (&dst)[8]){
  #pragma unroll
  for (int ks = 0; ks < 2; ++ks)
    #pragma unroll
    for (int mi = 0; mi < 4; ++mi) {
      const u16* p = h_in + (size_t)(rbase + mi) * 8192 + (kb * 2 + ks) * 512
                     + (lane >> 4) * 128 + (lane & 15) * 8;
      GLD16(dst[ks * 4 + mi].u, p);
    }
}

// ---------------------------------------------------------------------------
__global__ __launch_bounds__(512, 1) void lstm_persistent(
    const float* __restrict__ x, const u16* __restrict__ xf, int use_xf,
    const u16* __restrict__ WhhE, const u16* __restrict__ WhhD,
    const u16* __restrict__ xwE, const u16* __restrict__ xwD,
    const float* __restrict__ biasE, const float* __restrict__ biasD,
    u16* __restrict__ hb0, u16* __restrict__ hb1,
    float* __restrict__ dout,
    const float* __restrict__ WdT, const float* __restrict__ ldb,
    const float* __restrict__ loW, const float* __restrict__ lob,
    float* __restrict__ out, u32* __restrict__ cnt)
{
  extern __shared__ char smem[];
  const int tid = threadIdx.x;
  const int bid = blockIdx.x;
  const int mt = ((bid & 7) << 1) | ((bid >> 3) & 1);  // group shares XCD (perf only)
  const int nt = bid >> 4;
  const int wid = tid >> 6, lane = tid & 63;
  const int mh = wid >> 2, nh = wid & 3;
  const int lr = lane & 15, lgp = lane >> 4;
  u32* cptr = cnt + mt * 16;

  stage_whh(WhhE + (size_t)nt * WIMG2, smem, tid);
  bf16x8 whiR[2][2], wloR[2][2];
  load_xw(xwE + (size_t)(nt * 4 + nh) * 8 * 512, lane, whiR, wloR);
  f32x4 bvec[2];
  bvec[0] = *(const f32x4*)(biasE + nt * 128 + nh * 32 + lgp * 4);
  bvec[1] = *(const f32x4*)(biasE + nt * 128 + nh * 32 + 16 + lgp * 4);
  asm volatile("s_waitcnt vmcnt(0)" ::: "memory");
  __syncthreads();

  float creg[4][2];
  #pragma unroll
  for (int a = 0; a < 4; ++a) { creg[a][0] = 0.f; creg[a][1] = 0.f; }

  const int rbase = mt * 8 + mh * 4;
  int ev = 0;

  for (int t = 0; t < TENC + TDEC; ++t) {
    if (t == TENC) {
      __syncthreads();
      stage_whh(WhhD + (size_t)nt * WIMG2, smem, tid);
      load_xw(xwD + (size_t)(nt * 4 + nh) * 8 * 512, lane, whiR, wloR);
      bvec[0] = *(const f32x4*)(biasD + nt * 128 + nh * 32 + lgp * 4);
      bvec[1] = *(const f32x4*)(biasD + nt * 128 + nh * 32 + 16 + lgp * 4);
      asm volatile("s_waitcnt vmcnt(0)" ::: "memory");
      __syncthreads();
    }
    const u16* __restrict__ h_in  = (t & 1) ? hb1 : hb0;
    u16*       __restrict__ h_out = (t & 1) ? hb0 : hb1;

    f32x4 acc[4][2];
    #pragma unroll
    for (int a = 0; a < 4; ++a) {
      acc[a][0] = (f32x4){0.f, 0.f, 0.f, 0.f};
      acc[a][1] = (f32x4){0.f, 0.f, 0.f, 0.f};
    }

    // ---- x phase (independent of h): BEFORE the group barrier ----
    if (t > TENC) {
      // x = dout written by siblings last step; prev gbar's inv makes cached reads fresh
      #pragma unroll
      for (int mi = 0; mi < 4; ++mi) {
        const float* p = dout + (size_t)(mt * 128 + mh * 64 + mi * 16 + lr) * 64 + lgp * 8;
        #pragma unroll
        for (int ks = 0; ks < 2; ++ks) {
          float fv[8];
          float4 a0 = *(const float4*)(p + ks * 32);
          float4 a1 = *(const float4*)(p + ks * 32 + 4);
          fv[0]=a0.x; fv[1]=a0.y; fv[2]=a0.z; fv[3]=a0.w;
          fv[4]=a1.x; fv[5]=a1.y; fv[6]=a1.z; fv[7]=a1.w;
          bf16x8 xh, xl;
          cvt8(fv, xh, xl);
          #pragma unroll
          for (int ni = 0; ni < 2; ++ni) {
            acc[mi][ni] = MFMA16(whiR[ks][ni], xh, acc[mi][ni], 0, 0, 0);
            acc[mi][ni] = MFMA16(wloR[ks][ni], xh, acc[mi][ni], 0, 0, 0);
            acc[mi][ni] = MFMA16(whiR[ks][ni], xl, acc[mi][ni], 0, 0, 0);
          }
        }
      }
    } else if (use_xf) {
      int tx = (t < TENC) ? t : 255;
      #pragma unroll
      for (int mi = 0; mi < 4; ++mi) {
        const u16* fb = xf + ((size_t)tx * 128 + rbase + mi) * 2048;
        bf16x8 x0 = ld_bf8(fb +        lane * 8);
        bf16x8 x1 = ld_bf8(fb +  512 + lane * 8);
        bf16x8 l0 = ld_bf8(fb + 1024 + lane * 8);
        bf16x8 l1 = ld_bf8(fb + 1536 + lane * 8);
        #pragma unroll
        for (int ni = 0; ni < 2; ++ni) {
          acc[mi][ni] = MFMA16(whiR[0][ni], x0, acc[mi][ni], 0, 0, 0);
          acc[mi][ni] = MFMA16(wloR[0][ni], x0, acc[mi][ni], 0, 0, 0);
          acc[mi][ni] = MFMA16(whiR[1][ni], x1, acc[mi][ni], 0, 0, 0);
          acc[mi][ni] = MFMA16(wloR[1][ni], x1, acc[mi][ni], 0, 0, 0);
          acc[mi][ni] = MFMA16(whiR[0][ni], l0, acc[mi][ni], 0, 0, 0);
          acc[mi][ni] = MFMA16(whiR[1][ni], l1, acc[mi][ni], 0, 0, 0);
        }
      }
    } else {
      #pragma unroll
      for (int mi = 0; mi < 4; ++mi) {
        int brow = mt * 128 + mh * 64 + mi * 16 + lr;
        const float* p = x + ((size_t)brow * 256 + ((t < TENC) ? t : 255)) * 64;
        float fv[8];
        #pragma unroll
        for (int ks = 0; ks < 2; ++ks) {
          #pragma unroll
          for (int e = 0; e < 8; ++e) fv[e] = p[ks * 32 + lgp * 8 + e];
          bf16x8 xh, xl;
          cvt8(fv, xh, xl);
          #pragma unroll
          for (int ni = 0; ni < 2; ++ni) {
            acc[mi][ni] = MFMA16(whiR[ks][ni], xh, acc[mi][ni], 0, 0, 0);
            acc[mi][ni] = MFMA16(wloR[ks][ni], xh, acc[mi][ni], 0, 0, 0);
            acc[mi][ni] = MFMA16(whiR[ks][ni], xl, acc[mi][ni], 0, 0, 0);
          }
        }
      }
    }

    gbar(cptr, ev);   // h(t-1) at coherent point + L1/L2 invalidated

    // ---- h phase: cached frag loads, 3-deep pipeline, counted vmcnt ----
    {
      U4B hr[3][8];
      issue_h(h_in, rbase, lane, 0, hr[0]);
      issue_h(h_in, rbase, lane, 1, hr[1]);
      #pragma unroll
      for (int kb = 0; kb < 8; ++kb) {
        if (kb < 6) issue_h(h_in, rbase, lane, kb + 2, hr[(kb + 2) % 3]);
        if (kb < 6)       { asm volatile("s_waitcnt vmcnt(16)" ::: "memory"); }
        else if (kb == 6) { asm volatile("s_waitcnt vmcnt(8)" ::: "memory"); }
        else              { asm volatile("s_waitcnt vmcnt(0)" ::: "memory"); }
        __builtin_amdgcn_sched_barrier(0);
        #pragma unroll
        for (int ks = 0; ks < 2; ++ks) {
          bf16x8 wf[2];
          #pragma unroll
          for (int ni = 0; ni < 2; ++ni) {
            int crow = nh * 32 + ni * 16 + lr;
            wf[ni] = *(const bf16x8*)(smem + kb * 16384 + crow * 128 +
                                      (((ks * 4 + lgp) ^ (crow & 7)) << 4));
          }
          #pragma unroll
          for (int mi = 0; mi < 4; ++mi)
            #pragma unroll
            for (int ni = 0; ni < 2; ++ni)
              acc[mi][ni] = MFMA16(wf[ni], hr[kb % 3][ks * 4 + mi].b, acc[mi][ni], 0, 0, 0);
        }
      }
    }

    // ---- fused LSTM epilogue; h packed 2x bf16 -> u32 sc0sc1 store ----
    #pragma unroll
    for (int mi = 0; mi < 4; ++mi) {
      float hn2[2];
      #pragma unroll
      for (int ni = 0; ni < 2; ++ni) {
        f32x4 g = acc[mi][ni];
        float gi = g[0] + bvec[ni][0];
        float gf = g[1] + bvec[ni][1];
        float gg = g[2] + bvec[ni][2];
        float go = g[3] + bvec[ni][3];
        float c0 = creg[mi][ni];
        float cn = sigm(gf) * c0 + sigm(gi) * tanhfast(gg);
        hn2[ni] = sigm(go) * tanhfast(cn);
        creg[mi][ni] = cn;
      }
      u32 pk = (u32)f2bf_rne(hn2[0]) | ((u32)f2bf_rne(hn2[1]) << 16);
      u16* p = h_out + (size_t)(rbase + mi) * 8192 + nt * 512 + nh * 128 + lr * 8 + lgp * 2;
      HST32(p, pk);
    }

    // ---- decoder projections (bf16 h, broadcast cached loads) ----
    if (t >= TENC) {
      gbar(cptr, ev);   // h(t) complete group-wide + caches invalidated
      int d = t - TENC;
      int b = mt * 128 + nt * 8 + wid;
      int rb = b >> 4, lrb = b & 15;
      const u16* hbase = h_out + (size_t)rb * 8192 + lrb * 8;
      float a2 = ldb[lane];
      #pragma unroll 8
      for (int q = 0; q < 64; ++q) {
        uint4 hv = *(const uint4*)(hbase + q * 128);
        #pragma unroll
        for (int e = 0; e < 8; ++e) {
          float h8 = bf2f(((const u16*)&hv)[e]);
          a2 += h8 * WdT[(q * 8 + e) * 64 + lane];
        }
      }
      HST32((float*)(dout + (size_t)b * 64 + lane), a2);
      float yv = a2 * loW[lane];
      #pragma unroll
      for (int off2 = 32; off2; off2 >>= 1) yv += __shfl_xor(yv, off2, 64);
      if (lane == 0) out[(size_t)b * TDEC + d] = yv + lob[0];
      if (t < TENC + TDEC - 1) gbar(cptr, ev);   // dout visible for next x
    }
  }
}

// ---------------------------------------------------------------------------
extern "C" void kernel_launch(void* const* d_in, const int* in_sizes, int n_in,
                              void* d_out, int out_size, void* d_ws, size_t ws_size,
                              hipStream_t stream)
{
  const float* x    = (const float*)d_in[0];
  const float* eWih = (const float*)d_in[1];
  const float* eWhh = (const float*)d_in[2];
  const float* ebih = (const float*)d_in[3];
  const float* ebhh = (const float*)d_in[4];
  const float* dWih = (const float*)d_in[5];
  const float* dWhh = (const float*)d_in[6];
  const float* dbih = (const float*)d_in[7];
  const float* dbhh = (const float*)d_in[8];
  const float* ldW  = (const float*)d_in[9];
  const float* ldbp = (const float*)d_in[10];
  const float* loW  = (const float*)d_in[11];
  const float* lob  = (const float*)d_in[12];
  float* out = (float*)d_out;

  char* ws = (char*)d_ws;
  size_t o = 0;
  auto alloc = [&](size_t bytes){ size_t r = o; o += (bytes + 255) & ~(size_t)255; return r; };
  u16*   WhhIE = (u16*)  (ws + alloc((size_t)16 * WIMG2 * 2));
  u16*   WhhID = (u16*)  (ws + alloc((size_t)16 * WIMG2 * 2));
  u16*   xwE   = (u16*)  (ws + alloc((size_t)64 * 8 * 512 * 2));
  u16*   xwD   = (u16*)  (ws + alloc((size_t)64 * 8 * 512 * 2));
  float* biasE = (float*)(ws + alloc(2048 * 4));
  float* biasD = (float*)(ws + alloc(2048 * 4));
  float* WdT   = (float*)(ws + alloc((size_t)I_ * H_ * 4));
  u16*   hb0   = (u16*)  (ws + alloc((size_t)B_ * H_ * 2));
  u16*   hb1   = (u16*)  (ws + alloc((size_t)B_ * H_ * 2));
  float* dout  = (float*)(ws + alloc((size_t)B_ * I_ * 4));
  u32*   cnt   = (u32*)  (ws + alloc(16 * 64));
  size_t xf_off = alloc((size_t)256 * 128 * 2048 * 2);   // 128 MiB
  int use_xf = (o <= ws_size) ? 1 : 0;
  u16* xf = use_xf ? (u16*)(ws + xf_off) : (u16*)(ws);
  (void)in_sizes; (void)n_in; (void)out_size;

  pack_whh<<<(16 * WIMG2 + 255) / 256, 256, 0, stream>>>(eWhh, WhhIE);
  pack_whh<<<(16 * WIMG2 + 255) / 256, 256, 0, stream>>>(dWhh, WhhID);
  pack_xw<<<(64 * 8 * 512 + 255) / 256, 256, 0, stream>>>(eWih, xwE);
  pack_xw<<<(64 * 8 * 512 + 255) / 256, 256, 0, stream>>>(dWih, xwD);
  pack_bias<<<8, 256, 0, stream>>>(ebih, ebhh, biasE);
  pack_bias<<<8, 256, 0, stream>>>(dbih, dbhh, biasD);
  transpose_wd<<<(I_ * H_ + 255) / 256, 256, 0, stream>>>(ldW, WdT);
  if (use_xf)
    prefrag_x<<<256 * 128, 64, 0, stream>>>(x, xf);
  (void)hipMemsetAsync(hb0, 0, (size_t)B_ * H_ * 2, stream);
  (void)hipMemsetAsync(cnt, 0, 16 * 64, stream);

  static bool attr_set = false;
  if (!attr_set) {
    (void)hipFuncSetAttribute((const void*)lstm_persistent,
                              hipFuncAttributeMaxDynamicSharedMemorySize, 131072);
    attr_set = true;
  }

  const float* xp = x; const u16* xfp = xf; int uxf = use_xf;
  const u16 *we = WhhIE, *wd = WhhID, *xe = xwE, *xd = xwD;
  const float *be = biasE, *bd = biasD, *wdt = WdT, *lb = ldbp, *lw = loW, *lo2 = lob;
  u16 *h0 = hb0, *h1 = hb1;
  float *dp = dout, *op = out;
  u32* cp = cnt;
  void* kargs[] = { (void*)&xp, (void*)&xfp, (void*)&uxf, (void*)&we, (void*)&wd,
                    (void*)&xe, (void*)&xd, (void*)&be, (void*)&bd,
                    (void*)&h0, (void*)&h1, (void*)&dp, (void*)&wdt,
                    (void*)&lb, (void*)&lw, (void*)&lo2, (void*)&op, (void*)&cp };
  hipError_t e = hipLaunchCooperativeKernel((const void*)lstm_persistent,
                                            dim3(256), dim3(512), kargs, 131072, stream);
  if (e != hipSuccess) {
    lstm_persistent<<<256, 512, 131072, stream>>>(xp, xfp, uxf, we, wd, xe, xd,
                                                  be, bd, h0, h1, dp, wdt,
                                                  lb, lw, lo2, op, cp);
  }
}